// Round 3
// baseline (72842.377 us; speedup 1.0000x reference)
//
#include <hip/hip_runtime.h>
#include <hip/hip_bf16.h>

#define L_ 2
#define H_ 1024
#define Z_ 256
#define B_ 128
#define SRC_ 64
#define K_ 48
#define IN_ (Z_ + 1 + H_)   // 1281
#define TK 64

#define BH_ (B_ * H_)
#define BZ_ (B_ * Z_)
// scratch layout (floats): hs0[2]*BH | hs1[2]*BH | cs0 | cs1 | zcur(BZ) | attn | h0n | outb | qp | wctx
#define WS_FLOATS (11 * BH_ + BZ_)
__device__ float g_ws[WS_FLOATS];

__device__ __forceinline__ float sigm(float x) { return 1.0f / (1.0f + expf(-x)); }

// ---------------------------------------------------------------------------
// init: copy fp32 inputs -> state buffers
// ---------------------------------------------------------------------------
__global__ void k_init(const float* __restrict__ h0, const float* __restrict__ c0,
                       const float* __restrict__ z0,
                       float* __restrict__ hs0, float* __restrict__ hs1,
                       float* __restrict__ cs0, float* __restrict__ cs1,
                       float* __restrict__ zcur, float* __restrict__ outb) {
    int i = blockIdx.x * 256 + threadIdx.x;  // i < B_*H_
    hs0[i] = h0[i];
    hs1[i] = h0[BH_ + i];
    cs0[i] = c0[i];
    float c1 = c0[BH_ + i];
    cs1[i] = c1;
    outb[i] = c1;  // initial attention query = c0[-1]
    if (i < BZ_) zcur[i] = z0[i];
}

// ---------------------------------------------------------------------------
// LSTM cell: gates GEMM (x@Wih^T + h@Whh^T + biases) fused with cell update.
// CONCAT=true: x is virtual concat [z (256) | k (1) | attn (1024)], K=1281.
// CONCAT=false: x is a plain [B,H] buffer, K=1024.
// ---------------------------------------------------------------------------
template <bool CONCAT>
__global__ void k_lstm(const float* __restrict__ xin, const float* __restrict__ attn,
                       const int* __restrict__ kvec,
                       const float* __restrict__ hsr, float* __restrict__ hsw,
                       float* __restrict__ cs,
                       const float* __restrict__ Wih, const float* __restrict__ Whh,
                       const float* __restrict__ bih, const float* __restrict__ bhh,
                       float* __restrict__ hout, int step) {
    __shared__ float at[16][TK];
    const int tx = threadIdx.x;
    const int th = tx & 15, tb = tx >> 4;
    const int h = blockIdx.x * 16 + th;
    const int b0 = blockIdx.y * 16;
    const int b = b0 + tb;
    const int KX = CONCAT ? IN_ : H_;

    float acc0 = 0.f, acc1 = 0.f, acc2 = 0.f, acc3 = 0.f;
    const int r0 = 0 * H_ + h, r1 = 1 * H_ + h, r2 = 2 * H_ + h, r3 = 3 * H_ + h;

    // x part
    for (int k0 = 0; k0 < KX; k0 += TK) {
        int krem = min(TK, KX - k0);
        for (int i = tx; i < 16 * TK; i += 256) {
            int r = i >> 6, c = i & 63;
            int gk = k0 + c;
            float v = 0.f;
            if (CONCAT) {
                if (gk < KX) {
                    int bb = b0 + r;
                    if (gk < Z_) v = xin[bb * Z_ + gk];
                    else if (gk == Z_) v = (float)kvec[bb];
                    else v = attn[bb * H_ + (gk - Z_ - 1)];
                }
            } else {
                v = xin[(b0 + r) * H_ + gk];
            }
            at[r][c] = v;
        }
        __syncthreads();
#pragma unroll 8
        for (int c = 0; c < krem; ++c) {
            float a = at[tb][c];
            int k = k0 + c;
            acc0 += a * Wih[r0 * KX + k];
            acc1 += a * Wih[r1 * KX + k];
            acc2 += a * Wih[r2 * KX + k];
            acc3 += a * Wih[r3 * KX + k];
        }
        __syncthreads();
    }
    // h part (K = H_)
    for (int k0 = 0; k0 < H_; k0 += TK) {
        for (int i = tx; i < 16 * TK; i += 256) {
            int r = i >> 6, c = i & 63;
            at[r][c] = hsr[(b0 + r) * H_ + k0 + c];
        }
        __syncthreads();
#pragma unroll 8
        for (int c = 0; c < TK; ++c) {
            float a = at[tb][c];
            int k = k0 + c;
            acc0 += a * Whh[r0 * H_ + k];
            acc1 += a * Whh[r1 * H_ + k];
            acc2 += a * Whh[r2 * H_ + k];
            acc3 += a * Whh[r3 * H_ + k];
        }
        __syncthreads();
    }

    float gi = acc0 + bih[r0] + bhh[r0];
    float gf = acc1 + bih[r1] + bhh[r1];
    float gg = acc2 + bih[r2] + bhh[r2];
    float go = acc3 + bih[r3] + bhh[r3];

    float hold = hsr[b * H_ + h];
    float cold = cs[b * H_ + h];
    float cn = sigm(gf) * cold + sigm(gi) * tanhf(gg);
    float hn = sigm(go) * tanhf(cn);

    hout[b * H_ + h] = hn;                 // unfrozen output
    bool upd = step < kvec[b];
    hsw[b * H_ + h] = upd ? hn : hold;     // freeze-aware state
    if (upd) cs[b * H_ + h] = cn;
}

// ---------------------------------------------------------------------------
// mu/sigma projection + reparameterize + masked output write
// ---------------------------------------------------------------------------
__global__ void k_musig(const float* __restrict__ outb, const float* __restrict__ muW,
                        const float* __restrict__ mub, const float* __restrict__ sgW,
                        const float* __restrict__ sgb, const float* __restrict__ eps,
                        const int* __restrict__ kvec, float* __restrict__ zcur,
                        float* __restrict__ zout, float* __restrict__ muout,
                        float* __restrict__ sgout, int step) {
    __shared__ float at[16][TK];
    const int tx = threadIdx.x;
    const int tz = tx & 15, tb = tx >> 4;
    const int z = blockIdx.x * 16 + tz;
    const int b0 = blockIdx.y * 16;
    const int b = b0 + tb;
    float am = 0.f, as = 0.f;
    for (int k0 = 0; k0 < H_; k0 += TK) {
        for (int i = tx; i < 16 * TK; i += 256) {
            int r = i >> 6, c = i & 63;
            at[r][c] = outb[(b0 + r) * H_ + k0 + c];
        }
        __syncthreads();
#pragma unroll 8
        for (int c = 0; c < TK; ++c) {
            float a = at[tb][c];
            int k = k0 + c;
            am += a * muW[z * H_ + k];
            as += a * sgW[z * H_ + k];
        }
        __syncthreads();
    }
    am += mub[z];
    as += sgb[z];
    float zn = am + expf(as) * eps[(step * B_ + b) * Z_ + z];
    zcur[b * Z_ + z] = zn;  // feeds next step
    bool valid = step < kvec[b];
    int o = (b * K_ + step) * Z_ + z;
    zout[o] = valid ? zn : 0.f;
    muout[o] = valid ? am : 0.f;
    sgout[o] = valid ? as : 0.f;
}

// ---------------------------------------------------------------------------
// attention part 1: q' = q @ W_in^T
// ---------------------------------------------------------------------------
__global__ void k_qproj(const float* __restrict__ outb, const float* __restrict__ Win,
                        float* __restrict__ qp) {
    __shared__ float at[16][TK];
    const int tx = threadIdx.x;
    const int th = tx & 15, tb = tx >> 4;
    const int h = blockIdx.x * 16 + th;
    const int b0 = blockIdx.y * 16;
    const int b = b0 + tb;
    float acc = 0.f;
    for (int k0 = 0; k0 < H_; k0 += TK) {
        for (int i = tx; i < 16 * TK; i += 256) {
            int r = i >> 6, c = i & 63;
            at[r][c] = outb[(b0 + r) * H_ + k0 + c];
        }
        __syncthreads();
#pragma unroll 8
        for (int c = 0; c < TK; ++c) acc += at[tb][c] * Win[h * H_ + k0 + c];
        __syncthreads();
    }
    qp[b * H_ + h] = acc;
}

// ---------------------------------------------------------------------------
// attention part 2: scores -> softmax -> weighted context. One block per b.
// ---------------------------------------------------------------------------
__global__ void k_attn_ctx(const float* __restrict__ qp, const float* __restrict__ ctx,
                           float* __restrict__ wctx) {
    const int b = blockIdx.x;
    const int tx = threadIdx.x;
    __shared__ float ql[H_];
    __shared__ float part[SRC_][4];
    __shared__ float align[SRC_];
    for (int i = tx; i < H_; i += 256) ql[i] = qp[b * H_ + i];
    __syncthreads();
    int s = tx >> 2, q = tx & 3;
    float p = 0.f;
    const float* crow = ctx + (size_t)(b * SRC_ + s) * H_;
    for (int k = q * 256; k < q * 256 + 256; ++k) p += ql[k] * crow[k];
    part[s][q] = p;
    __syncthreads();
    if (tx == 0) {
        float sc[SRC_];
        float mx = -1e30f;
        for (int s2 = 0; s2 < SRC_; ++s2) {
            float v = part[s2][0] + part[s2][1] + part[s2][2] + part[s2][3];
            sc[s2] = v;
            mx = fmaxf(mx, v);
        }
        float sum = 0.f;
        for (int s2 = 0; s2 < SRC_; ++s2) {
            float e = expf(sc[s2] - mx);
            align[s2] = e;
            sum += e;
        }
        float inv = 1.f / sum;
        for (int s2 = 0; s2 < SRC_; ++s2) align[s2] *= inv;
    }
    __syncthreads();
    for (int h = tx; h < H_; h += 256) {
        float acc = 0.f;
        for (int s2 = 0; s2 < SRC_; ++s2)
            acc += align[s2] * ctx[(size_t)(b * SRC_ + s2) * H_ + h];
        wctx[b * H_ + h] = acc;
    }
}

// ---------------------------------------------------------------------------
// attention part 3: attn = tanh(concat(weighted, q) @ W_out^T)
// ---------------------------------------------------------------------------
__global__ void k_attn_out(const float* __restrict__ wctx, const float* __restrict__ outb,
                           const float* __restrict__ Wout, float* __restrict__ attn) {
    __shared__ float at[16][TK];
    const int tx = threadIdx.x;
    const int th = tx & 15, tb = tx >> 4;
    const int h = blockIdx.x * 16 + th;
    const int b0 = blockIdx.y * 16;
    const int b = b0 + tb;
    float acc = 0.f;
    for (int k0 = 0; k0 < H_; k0 += TK) {  // weighted part
        for (int i = tx; i < 16 * TK; i += 256) {
            int r = i >> 6, c = i & 63;
            at[r][c] = wctx[(b0 + r) * H_ + k0 + c];
        }
        __syncthreads();
#pragma unroll 8
        for (int c = 0; c < TK; ++c) acc += at[tb][c] * Wout[h * (2 * H_) + k0 + c];
        __syncthreads();
    }
    for (int k0 = 0; k0 < H_; k0 += TK) {  // q part
        for (int i = tx; i < 16 * TK; i += 256) {
            int r = i >> 6, c = i & 63;
            at[r][c] = outb[(b0 + r) * H_ + k0 + c];
        }
        __syncthreads();
#pragma unroll 8
        for (int c = 0; c < TK; ++c)
            acc += at[tb][c] * Wout[h * (2 * H_) + H_ + k0 + c];
        __syncthreads();
    }
    attn[b * H_ + h] = tanhf(acc);
}

// ---------------------------------------------------------------------------
// final: state -> h_f / c_f outputs
// ---------------------------------------------------------------------------
__global__ void k_final(const float* __restrict__ hs0, const float* __restrict__ hs1,
                        const float* __restrict__ cs0, const float* __restrict__ cs1,
                        float* __restrict__ out) {
    int i = blockIdx.x * 256 + threadIdx.x;  // i < B_*H_
    float* hf = out + (size_t)3 * B_ * K_ * Z_;
    float* cf = hf + 2 * BH_;
    hf[i] = hs0[i];
    hf[BH_ + i] = hs1[i];
    cf[i] = cs0[i];
    cf[BH_ + i] = cs1[i];
}

extern "C" void kernel_launch(void* const* d_in, const int* in_sizes, int n_in,
                              void* d_out, int out_size, void* d_ws, size_t ws_size,
                              hipStream_t stream) {
    (void)in_sizes; (void)n_in; (void)out_size; (void)d_ws; (void)ws_size;
    const float* h0 = (const float*)d_in[0];
    const float* c0 = (const float*)d_in[1];
    const float* ctx = (const float*)d_in[2];
    const float* z0 = (const float*)d_in[3];
    const int* kvec = (const int*)d_in[4];
    const float* eps = (const float*)d_in[5];
    const float* Wih0 = (const float*)d_in[6];
    const float* Whh0 = (const float*)d_in[7];
    const float* bih0 = (const float*)d_in[8];
    const float* bhh0 = (const float*)d_in[9];
    const float* Wih1 = (const float*)d_in[10];
    const float* Whh1 = (const float*)d_in[11];
    const float* bih1 = (const float*)d_in[12];
    const float* bhh1 = (const float*)d_in[13];
    const float* Win = (const float*)d_in[14];
    const float* Wout = (const float*)d_in[15];
    const float* muW = (const float*)d_in[16];
    const float* mub = (const float*)d_in[17];
    const float* sgW = (const float*)d_in[18];
    const float* sgb = (const float*)d_in[19];
    float* out = (float*)d_out;

    // scratch = static device global
    float* ws = nullptr;
    hipGetSymbolAddress((void**)&ws, HIP_SYMBOL(g_ws));

    float* hs0buf[2] = {ws, ws + BH_};
    float* hs1buf[2] = {ws + 2 * BH_, ws + 3 * BH_};
    float* cs0 = ws + 4 * BH_;
    float* cs1 = ws + 5 * BH_;
    float* zcur = ws + 6 * BH_;      // B_*Z_
    float* attn = zcur + BZ_;        // B_*H_
    float* h0n = attn + BH_;
    float* outb = h0n + BH_;
    float* qp = outb + BH_;
    float* wctx = qp + BH_;

    dim3 blk(256);
    dim3 g_lstm(H_ / 16, B_ / 16);   // (64, 8)
    dim3 g_musig(Z_ / 16, B_ / 16);  // (16, 8)
    dim3 g_bh(BH_ / 256);            // 512

    k_init<<<g_bh, blk, 0, stream>>>(h0, c0, z0, hs0buf[0], hs1buf[0], cs0, cs1, zcur, outb);
    // initial attention with q = c0[-1] (staged in outb)
    k_qproj<<<g_lstm, blk, 0, stream>>>(outb, Win, qp);
    k_attn_ctx<<<dim3(B_), blk, 0, stream>>>(qp, ctx, wctx);
    k_attn_out<<<g_lstm, blk, 0, stream>>>(wctx, outb, Wout, attn);

    for (int i = 0; i < K_; ++i) {
        int rd = i & 1, wr = rd ^ 1;
        k_lstm<true><<<g_lstm, blk, 0, stream>>>(zcur, attn, kvec, hs0buf[rd], hs0buf[wr],
                                                 cs0, Wih0, Whh0, bih0, bhh0, h0n, i);
        k_lstm<false><<<g_lstm, blk, 0, stream>>>(h0n, nullptr, kvec, hs1buf[rd], hs1buf[wr],
                                                  cs1, Wih1, Whh1, bih1, bhh1, outb, i);
        k_musig<<<g_musig, blk, 0, stream>>>(outb, muW, mub, sgW, sgb, eps, kvec, zcur, out,
                                             out + (size_t)B_ * K_ * Z_,
                                             out + (size_t)2 * B_ * K_ * Z_, i);
        if (i + 1 < K_) {  // last step's attention is discarded by the scan
            k_qproj<<<g_lstm, blk, 0, stream>>>(outb, Win, qp);
            k_attn_ctx<<<dim3(B_), blk, 0, stream>>>(qp, ctx, wctx);
            k_attn_out<<<g_lstm, blk, 0, stream>>>(wctx, outb, Wout, attn);
        }
    }
    // K_=48 even -> final h-state lives in buffer 0
    k_final<<<g_bh, blk, 0, stream>>>(hs0buf[0], hs1buf[0], cs0, cs1, out);
}

// Round 4
// 6117.496 us; speedup vs baseline: 11.9072x; 11.9072x over previous
//
#include <hip/hip_runtime.h>
#include <hip/hip_bf16.h>

#define L_ 2
#define H_ 1024
#define Z_ 256
#define B_ 128
#define SRC_ 64
#define K_ 48
#define BH_ (B_ * H_)
#define BZ_ (B_ * Z_)
#define KA_ 2304   // lstm0 GEMM K: z(256) | attn(1024) | h0(1024)
#define KB_ 2048   // lstm1 GEMM K: h0n(1024) | h1(1024)

typedef unsigned short u16;
typedef __attribute__((ext_vector_type(8))) short short8;
typedef __attribute__((ext_vector_type(4))) float f32x4;

// ---------------- static device workspace ----------------
__device__ u16 g_Wc0[4096 * KA_];     // lstm0 weights, gate-interleaved rows [4h+g][KA]
__device__ u16 g_Wc1[4096 * KB_];     // lstm1 weights
__device__ u16 g_Wmq[512 * 1024];     // mu/sigma rows interleaved [2z+sel][1024]
__device__ u16 g_Woutb[1024 * 2048];  // Wout bf16
__device__ u16 g_WinT[1024 * 1024];   // Win transposed bf16
__device__ u16 g_ctxb[8192 * 1024];   // context bf16 [B*SRC][H]
__device__ u16 g_ctxW[8192 * 1024];   // ctx @ Wout[:, :H]^T
__device__ u16 g_ctxWin[8192 * 1024]; // ctx @ Win
__device__ u16 g_XA[2][B_ * KA_];     // lstm0 input (dbl-buffered): z|attn|h0state
__device__ u16 g_XB[2][B_ * KB_];     // lstm1 input: h0n|h1state
__device__ u16 g_XC[B_ * H_];         // h1n unfrozen (query / musig input)
__device__ float g_pb0[4096], g_pb1[4096], g_pbmq[512], g_wk0[4096];
__device__ float g_cs0[BH_], g_cs1[BH_], g_align[B_ * SRC_];

__device__ __forceinline__ float sigm(float x) { return 1.0f / (1.0f + expf(-x)); }
__device__ __forceinline__ u16 f2b(float f) {
    union { float f; unsigned u; } x; x.f = f;
    unsigned r = x.u + 0x7fffu + ((x.u >> 16) & 1u);
    return (u16)(r >> 16);
}
__device__ __forceinline__ float b2f(u16 s) {
    union { unsigned u; float f; } x; x.u = ((unsigned)s) << 16;
    return x.f;
}

// ---------------- prep kernels ----------------
__global__ void prep_wc0(const float* __restrict__ Wih, const float* __restrict__ Whh,
                         const float* __restrict__ bih, const float* __restrict__ bhh) {
    int n = blockIdx.x;                 // interleaved row: n = 4h+g
    int h = n >> 2, g = n & 3, r = g * 1024 + h;
    u16* row = g_Wc0 + (size_t)n * KA_;
    for (int j = threadIdx.x; j < KA_; j += 256) {
        float v = (j < 256) ? Wih[(size_t)r * 1281 + j]
                : (j < 1280) ? Wih[(size_t)r * 1281 + j + 1]
                             : Whh[(size_t)r * 1024 + (j - 1280)];
        row[j] = f2b(v);
    }
    if (threadIdx.x == 0) {
        g_wk0[n] = Wih[(size_t)r * 1281 + 256];
        g_pb0[n] = bih[r] + bhh[r];
    }
}

__global__ void prep_wc1(const float* __restrict__ Wih, const float* __restrict__ Whh,
                         const float* __restrict__ bih, const float* __restrict__ bhh) {
    int n = blockIdx.x;
    int h = n >> 2, g = n & 3, r = g * 1024 + h;
    u16* row = g_Wc1 + (size_t)n * KB_;
    for (int j = threadIdx.x; j < KB_; j += 256) {
        float v = (j < 1024) ? Wih[(size_t)r * 1024 + j] : Whh[(size_t)r * 1024 + (j - 1024)];
        row[j] = f2b(v);
    }
    if (threadIdx.x == 0) g_pb1[n] = bih[r] + bhh[r];
}

__global__ void prep_wmq(const float* __restrict__ muW, const float* __restrict__ mub,
                         const float* __restrict__ sgW, const float* __restrict__ sgb) {
    int n = blockIdx.x;                 // n = 2z+sel
    int z = n >> 1, sel = n & 1;
    const float* src = sel ? sgW : muW;
    u16* row = g_Wmq + (size_t)n * 1024;
    for (int j = threadIdx.x; j < 1024; j += 256) row[j] = f2b(src[(size_t)z * 1024 + j]);
    if (threadIdx.x == 0) g_pbmq[n] = sel ? sgb[z] : mub[z];
}

__global__ void prep_copy(const float* __restrict__ in, u16* __restrict__ out, int n) {
    for (int i = blockIdx.x * 256 + threadIdx.x; i < n; i += gridDim.x * 256)
        out[i] = f2b(in[i]);
}

__global__ void prep_winT(const float* __restrict__ Win) {
    __shared__ float t[32][33];
    int bx = blockIdx.x * 32, by = blockIdx.y * 32;
    int tx = threadIdx.x & 31, ty0 = threadIdx.x >> 5;
    for (int it = 0; it < 4; ++it) {
        int ty = ty0 + it * 8;
        t[ty][tx] = Win[(size_t)(by + ty) * 1024 + bx + tx];
    }
    __syncthreads();
    for (int it = 0; it < 4; ++it) {
        int ty = ty0 + it * 8;
        g_WinT[(size_t)(bx + ty) * 1024 + by + tx] = f2b(t[tx][ty]);
    }
}

// ---------------- generic MFMA K-loop ----------------
template <int K>
__device__ __forceinline__ void mm_loop(const u16* __restrict__ A, int sA,
                                        const u16* __restrict__ W, int sW,
                                        int n0, int mbase, int lane,
                                        f32x4& acc0, f32x4& acc1) {
    const int quad = lane >> 4, l16 = lane & 15;
    const u16* pa0 = A + (size_t)(mbase + l16) * sA + quad * 8;
    const u16* pa1 = pa0 + (size_t)16 * sA;
    const u16* pw = W + (size_t)(n0 + l16) * sW + quad * 8;
#pragma unroll 4
    for (int k0 = 0; k0 < K; k0 += 32) {
        short8 a0 = *(const short8*)(const void*)(pa0 + k0);
        short8 a1 = *(const short8*)(const void*)(pa1 + k0);
        short8 b = *(const short8*)(const void*)(pw + k0);
        acc0 = __builtin_amdgcn_mfma_f32_16x16x32_bf16(a0, b, acc0, 0, 0, 0);
        acc1 = __builtin_amdgcn_mfma_f32_16x16x32_bf16(a1, b, acc1, 0, 0, 0);
    }
}

__device__ __forceinline__ void stage_C(float (*ct)[17], int lane, int wave,
                                        const f32x4& acc0, const f32x4& acc1) {
    int quad = lane >> 4, l16 = lane & 15;
    int m0 = wave * 32 + quad * 4;
#pragma unroll
    for (int r = 0; r < 4; ++r) {
        ct[m0 + r][l16] = acc0[r];
        ct[m0 + 16 + r][l16] = acc1[r];
    }
}

// ---------------- LSTM GEMM+cell (LAYER 0 or 1) ----------------
template <int LAYER>
__global__ __launch_bounds__(256) void k_lstm_mm(const int* __restrict__ kvec, int step) {
    constexpr int K = (LAYER == 0) ? KA_ : KB_;
    const int p = step & 1;
    const u16* A = (LAYER == 0) ? g_XA[p] : g_XB[p];
    const u16* W = (LAYER == 0) ? g_Wc0 : g_Wc1;
    const float* pb = (LAYER == 0) ? g_pb0 : g_pb1;
    float* cs = (LAYER == 0) ? g_cs0 : g_cs1;
    const u16* stOld = (LAYER == 0) ? (g_XA[p] + 1280) : (g_XB[p] + 1024);
    u16* stNew = (LAYER == 0) ? (g_XA[1 - p] + 1280) : (g_XB[1 - p] + 1024);
    const int stStride = (LAYER == 0) ? KA_ : KB_;
    u16* hout = (LAYER == 0) ? g_XB[p] : g_XC;
    const int hoStride = (LAYER == 0) ? KB_ : 1024;

    const int tid = threadIdx.x, wave = tid >> 6, lane = tid & 63;
    const int n0 = blockIdx.x * 16;
    __shared__ float ct[128][17];
    f32x4 acc0 = {0.f, 0.f, 0.f, 0.f}, acc1 = {0.f, 0.f, 0.f, 0.f};
    mm_loop<K>(A, K, W, K, n0, wave * 32, lane, acc0, acc1);
    stage_C(ct, lane, wave, acc0, acc1);
    __syncthreads();

    for (int u = tid; u < 512; u += 256) {
        int b = u & 127, hl = u >> 7;       // hl in 0..3
        float kf = (float)kvec[b];
        float gi = ct[b][4 * hl + 0] + pb[n0 + 4 * hl + 0];
        float gf = ct[b][4 * hl + 1] + pb[n0 + 4 * hl + 1];
        float gg = ct[b][4 * hl + 2] + pb[n0 + 4 * hl + 2];
        float go = ct[b][4 * hl + 3] + pb[n0 + 4 * hl + 3];
        if (LAYER == 0) {
            gi += kf * g_wk0[n0 + 4 * hl + 0];
            gf += kf * g_wk0[n0 + 4 * hl + 1];
            gg += kf * g_wk0[n0 + 4 * hl + 2];
            go += kf * g_wk0[n0 + 4 * hl + 3];
        }
        int hg = blockIdx.x * 4 + hl;
        float cold = cs[b * 1024 + hg];
        float cn = sigm(gf) * cold + sigm(gi) * tanhf(gg);
        float hn = sigm(go) * tanhf(cn);
        hout[(size_t)b * hoStride + hg] = f2b(hn);      // unfrozen output
        bool upd = step < kvec[b];
        if (upd) {
            stNew[(size_t)b * stStride + hg] = f2b(hn);
            cs[b * 1024 + hg] = cn;
        } else {
            stNew[(size_t)b * stStride + hg] = stOld[(size_t)b * stStride + hg];
        }
    }
}

// ---------------- fused musig (blocks 0-31) + scores/softmax (blocks 32-159) ----------------
// mode: 0 normal, 1 init (skip musig), 2 last (skip scores)
__global__ __launch_bounds__(256) void k_mq(const float* __restrict__ eps,
                                            const int* __restrict__ kvec,
                                            float* __restrict__ out, int step, int mode) {
    __shared__ float smem[2304];
    const int tid = threadIdx.x;
    if (blockIdx.x < 32) {
        if (mode == 1) return;
        // ---- musig GEMM: N=512 rows (2z+sel), K=1024, A=g_XC ----
        const int wave = tid >> 6, lane = tid & 63;
        const int n0 = blockIdx.x * 16;
        float (*ct)[17] = (float(*)[17])smem;
        f32x4 acc0 = {0.f, 0.f, 0.f, 0.f}, acc1 = {0.f, 0.f, 0.f, 0.f};
        mm_loop<1024>(g_XC, 1024, g_Wmq, 1024, n0, wave * 32, lane, acc0, acc1);
        stage_C(ct, lane, wave, acc0, acc1);
        __syncthreads();
        u16* zdst = g_XA[(step + 1) & 1];
        float* out_z = out;
        float* out_mu = out + (size_t)B_ * K_ * Z_;
        float* out_sg = out + (size_t)2 * B_ * K_ * Z_;
        for (int u = tid; u < 1024; u += 256) {
            int b = u & 127, zl = u >> 7;   // zl 0..7
            float mu = ct[b][2 * zl] + g_pbmq[n0 + 2 * zl];
            float sg = ct[b][2 * zl + 1] + g_pbmq[n0 + 2 * zl + 1];
            int zg = (n0 >> 1) + zl;
            float e = eps[((size_t)step * B_ + b) * Z_ + zg];
            float zn = mu + expf(sg) * e;
            zdst[(size_t)b * KA_ + zg] = f2b(zn);
            bool valid = step < kvec[b];
            size_t o = ((size_t)b * K_ + step) * Z_ + zg;
            out_z[o] = valid ? zn : 0.f;
            out_mu[o] = valid ? mu : 0.f;
            out_sg[o] = valid ? sg : 0.f;
        }
    } else {
        if (mode == 2) return;
        // ---- scores + softmax for one b ----
        const int b = blockIdx.x - 32;
        float* qf = smem;                   // [1024]
        float (*parts)[4] = (float(*)[4])(smem + 1024);
        for (int i = tid; i < 1024; i += 256) qf[i] = b2f(g_XC[b * 1024 + i]);
        __syncthreads();
        int s = tid >> 2, part = tid & 3;
        const u16* row = g_ctxWin + ((size_t)(b * SRC_ + s)) * 1024 + part * 256;
        float pacc = 0.f;
        for (int j = 0; j < 256; j += 8) {
            short8 v = *(const short8*)(const void*)(row + j);
#pragma unroll
            for (int t = 0; t < 8; ++t) pacc += qf[part * 256 + j + t] * b2f(((u16*)&v)[t]);
        }
        parts[s][part] = pacc;
        __syncthreads();
        if (tid == 0) {
            float sc[SRC_], mx = -1e30f;
            for (int s2 = 0; s2 < SRC_; ++s2) {
                float v = parts[s2][0] + parts[s2][1] + parts[s2][2] + parts[s2][3];
                sc[s2] = v; mx = fmaxf(mx, v);
            }
            float sum = 0.f;
            for (int s2 = 0; s2 < SRC_; ++s2) { sc[s2] = expf(sc[s2] - mx); sum += sc[s2]; }
            float inv = 1.f / sum;
            for (int s2 = 0; s2 < SRC_; ++s2) g_align[b * SRC_ + s2] = sc[s2] * inv;
        }
    }
}

// ---------------- attn_out: q-part GEMM + align contraction, dest parity dp ----------------
__global__ __launch_bounds__(256) void k_attn(int dp) {
    __shared__ float smem[2304];
    float (*ct)[17] = (float(*)[17])smem;
    const int tid = threadIdx.x, wave = tid >> 6, lane = tid & 63;
    const int n0 = blockIdx.x * 16;
    f32x4 acc0 = {0.f, 0.f, 0.f, 0.f}, acc1 = {0.f, 0.f, 0.f, 0.f};
    mm_loop<1024>(g_XC, 1024, g_Woutb + 1024, 2048, n0, wave * 32, lane, acc0, acc1);
    stage_C(ct, lane, wave, acc0, acc1);
    __syncthreads();
    int b = tid >> 1, h8 = tid & 1;         // 8 cols each
    const u16* base = g_ctxW + (size_t)b * SRC_ * 1024 + n0 + h8 * 8;
    float a8[8] = {0.f, 0.f, 0.f, 0.f, 0.f, 0.f, 0.f, 0.f};
    for (int s = 0; s < SRC_; ++s) {
        float al = g_align[b * SRC_ + s];
        short8 v = *(const short8*)(const void*)(base + (size_t)s * 1024);
#pragma unroll
        for (int j = 0; j < 8; ++j) a8[j] += al * b2f(((u16*)&v)[j]);
    }
    u16 ov[8];
#pragma unroll
    for (int j = 0; j < 8; ++j) ov[j] = f2b(tanhf(a8[j] + ct[b][h8 * 8 + j]));
    *(short8*)(void*)(g_XA[dp] + (size_t)b * KA_ + 256 + n0 + h8 * 8) = *(short8*)(void*)ov;
}

// ---------------- init / final ----------------
__global__ void k_init(const float* __restrict__ h0, const float* __restrict__ c0,
                       const float* __restrict__ z0) {
    int i = blockIdx.x * 256 + threadIdx.x;  // i < BH_
    int b = i >> 10, h = i & 1023;
    g_XA[0][(size_t)b * KA_ + 1280 + h] = f2b(h0[i]);            // h0 layer0 state
    g_XB[0][(size_t)b * KB_ + 1024 + h] = f2b(h0[BH_ + i]);      // h layer1 state
    g_XC[i] = f2b(c0[BH_ + i]);                                  // initial query c0[-1]
    g_cs0[i] = c0[i];
    g_cs1[i] = c0[BH_ + i];
    if (i < BZ_) {
        int bb = i >> 8, z = i & 255;
        g_XA[0][(size_t)bb * KA_ + z] = f2b(z0[i]);
    }
}

__global__ void k_final(float* __restrict__ out) {
    int i = blockIdx.x * 256 + threadIdx.x;  // i < BH_
    int b = i >> 10, h = i & 1023;
    float* hf = out + (size_t)3 * B_ * K_ * Z_;
    float* cf = hf + 2 * BH_;
    hf[i] = b2f(g_XA[0][(size_t)b * KA_ + 1280 + h]);
    hf[BH_ + i] = b2f(g_XB[0][(size_t)b * KB_ + 1024 + h]);
    cf[i] = g_cs0[i];
    cf[BH_ + i] = g_cs1[i];
}

// ---------------- prep GEMM: Out[m][n] = sum_k A[m][k]*W[n][k], bf16 out ----------------
__global__ __launch_bounds__(256) void k_gemm_prep(const u16* __restrict__ A, int sA,
                                                   const u16* __restrict__ W, int sW,
                                                   u16* __restrict__ Out, int sO) {
    const int tid = threadIdx.x, wave = tid >> 6, lane = tid & 63;
    const int n0 = blockIdx.x * 16;
    const int mb = blockIdx.y * 128;
    const int quad = lane >> 4, l16 = lane & 15;
    f32x4 acc0 = {0.f, 0.f, 0.f, 0.f}, acc1 = {0.f, 0.f, 0.f, 0.f};
    mm_loop<1024>(A + (size_t)mb * sA, sA, W, sW, n0, wave * 32, lane, acc0, acc1);
#pragma unroll
    for (int r = 0; r < 4; ++r) {
        int m0 = mb + wave * 32 + quad * 4 + r;
        Out[(size_t)m0 * sO + n0 + l16] = f2b(acc0[r]);
        Out[(size_t)(m0 + 16) * sO + n0 + l16] = f2b(acc1[r]);
    }
}

extern "C" void kernel_launch(void* const* d_in, const int* in_sizes, int n_in,
                              void* d_out, int out_size, void* d_ws, size_t ws_size,
                              hipStream_t stream) {
    (void)in_sizes; (void)n_in; (void)out_size; (void)d_ws; (void)ws_size;
    const float* h0 = (const float*)d_in[0];
    const float* c0 = (const float*)d_in[1];
    const float* ctx = (const float*)d_in[2];
    const float* z0 = (const float*)d_in[3];
    const int* kvec = (const int*)d_in[4];
    const float* eps = (const float*)d_in[5];
    const float* Wih0 = (const float*)d_in[6];
    const float* Whh0 = (const float*)d_in[7];
    const float* bih0 = (const float*)d_in[8];
    const float* bhh0 = (const float*)d_in[9];
    const float* Wih1 = (const float*)d_in[10];
    const float* Whh1 = (const float*)d_in[11];
    const float* bih1 = (const float*)d_in[12];
    const float* bhh1 = (const float*)d_in[13];
    const float* Win = (const float*)d_in[14];
    const float* Wout = (const float*)d_in[15];
    const float* muW = (const float*)d_in[16];
    const float* mub = (const float*)d_in[17];
    const float* sgW = (const float*)d_in[18];
    const float* sgb = (const float*)d_in[19];
    float* out = (float*)d_out;

    dim3 blk(256);
    // ---- one-time prep ----
    prep_wc0<<<4096, blk, 0, stream>>>(Wih0, Whh0, bih0, bhh0);
    prep_wc1<<<4096, blk, 0, stream>>>(Wih1, Whh1, bih1, bhh1);
    prep_wmq<<<512, blk, 0, stream>>>(muW, mub, sgW, sgb);
    {
        u16* woutb; hipGetSymbolAddress((void**)&woutb, HIP_SYMBOL(g_Woutb));
        u16* ctxb; hipGetSymbolAddress((void**)&ctxb, HIP_SYMBOL(g_ctxb));
        u16* winT; hipGetSymbolAddress((void**)&winT, HIP_SYMBOL(g_WinT));
        u16* ctxW; hipGetSymbolAddress((void**)&ctxW, HIP_SYMBOL(g_ctxW));
        u16* ctxWin; hipGetSymbolAddress((void**)&ctxWin, HIP_SYMBOL(g_ctxWin));
        prep_copy<<<2048, blk, 0, stream>>>(Wout, woutb, 1024 * 2048);
        prep_copy<<<8192, blk, 0, stream>>>(ctx, ctxb, 8192 * 1024);
        prep_winT<<<dim3(32, 32), blk, 0, stream>>>(Win);
        // ctxW = ctx @ Wout[:, :1024]^T ; ctxWin = ctx @ Win
        k_gemm_prep<<<dim3(64, 64), blk, 0, stream>>>(ctxb, 1024, woutb, 2048, ctxW, 1024);
        k_gemm_prep<<<dim3(64, 64), blk, 0, stream>>>(ctxb, 1024, winT, 1024, ctxWin, 1024);
    }
    // ---- init state + initial attention (q = c0[-1]) ----
    k_init<<<BH_ / 256, blk, 0, stream>>>(h0, c0, z0);
    k_mq<<<160, blk, 0, stream>>>(eps, kvec, out, 0, /*mode=*/1);  // scores only
    k_attn<<<64, blk, 0, stream>>>(/*dp=*/0);                       // attn0 -> XA[0]

    // ---- 48 steps ----
    for (int i = 0; i < K_; ++i) {
        k_lstm_mm<0><<<256, blk, 0, stream>>>(kvec, i);
        k_lstm_mm<1><<<256, blk, 0, stream>>>(kvec, i);
        k_mq<<<160, blk, 0, stream>>>(eps, kvec, out, i, (i == K_ - 1) ? 2 : 0);
        if (i + 1 < K_) k_attn<<<64, blk, 0, stream>>>((i + 1) & 1);
    }
    // K_=48 even -> final states in parity-0 buffers
    k_final<<<BH_ / 256, blk, 0, stream>>>(out);
}